// Round 3
// baseline (1736.233 us; speedup 1.0000x reference)
//
#include <hip/hip_runtime.h>

namespace {

constexpr int kNIn = 128;
constexpr int kNRec = 128;
constexpr int BR = 64;              // rows per block
constexpr int KC = 32;              // k-chunk staged in LDS
constexpr int NCH = kNIn / KC;      // 4 chunks
constexpr int NQ = kNIn / 4;        // 32 k-quads over the whole k range

typedef float vfloat4 __attribute__((ext_vector_type(4)));

__device__ __forceinline__ float fcomp(const float4 f, int i) {
  switch (i & 3) {
    case 0: return f.x;
    case 1: return f.y;
    case 2: return f.z;
    default: return f.w;
  }
}

__device__ __forceinline__ void nt_store4(float* p, float a, float b, float c,
                                          float d) {
  vfloat4 val = {a, b, c, d};
  __builtin_nontemporal_store(val, reinterpret_cast<vfloat4*>(p));
}

// Block: 256 threads, tile 64 rows x 128 cols; thread tile 4 rows x 8 cols.
// Weights staged in LDS in k-chunks of 32 (2 x 16 KB = 32 KB, 4 blocks/CU).
//
// R2 post-mortem: VGPR_Count=64 proved the x/z operand pipeline was
// collapsed by the scheduler (needs ~96 live regs); loads were sunk to
// just-before-use -> ~1.2K cy exposed vector-load latency per kq = the
// 284us wall (VALUBusy 26%). Fix: sched_barrier(0) fence between each
// kq's prefetch loads and the FMA block so the loads cannot sink; budget
// at launch_bounds(256,4) is 128 VGPR, pipeline needs ~120.
// Stores are nontemporal (R2 showed cached stores ADD 77MB of RFO/evict
// fetch at zero time benefit; 2.3x WRITE_SIZE is counter semantics, not
// a store-pattern artifact).
__global__ __launch_bounds__(256, 4) void lif_fused(
    const float* __restrict__ x, const float* __restrict__ z,
    const float* __restrict__ v, const float* __restrict__ t,
    const float* __restrict__ w_in, const float* __restrict__ w_rec,
    float* __restrict__ out, int batch) {
  __shared__ float swi[KC][kNRec];
  __shared__ float swr[KC][kNRec];

  const int tid = threadIdx.x;
  const int tc = tid & 15;          // 16 col groups
  const int tr = tid >> 4;          // 16 row groups x 4 rows = 64 rows
  const int row0 = blockIdx.x * BR + tr * 4;
  const int c0 = tc * 4;

  float acc[4][8];
#pragma unroll
  for (int i = 0; i < 4; ++i)
#pragma unroll
    for (int c = 0; c < 8; ++c) acc[i][c] = 0.0f;

  const float4* __restrict__ x4 =
      reinterpret_cast<const float4*>(x) + (size_t)row0 * NQ;
  const float4* __restrict__ z4 =
      reinterpret_cast<const float4*>(z) + (size_t)row0 * NQ;
  float4* swi4 = reinterpret_cast<float4*>(&swi[0][0]);
  float4* swr4 = reinterpret_cast<float4*>(&swr[0][0]);

  // Prime the x/z operand pipeline with quad 0 (in flight during chunk-0
  // weight staging + barrier).
  float4 axc[4], azc[4];
#pragma unroll
  for (int i = 0; i < 4; ++i) {
    axc[i] = x4[(size_t)i * NQ];
    azc[i] = z4[(size_t)i * NQ];
  }

  for (int ch = 0; ch < NCH; ++ch) {
    // Stage this chunk's weight rows (KC x 128 per matrix) into LDS.
    // Loads are issued before the chunk-open barrier so they fly during it.
    const float4* gwi =
        reinterpret_cast<const float4*>(w_in + (size_t)ch * KC * kNRec);
    const float4* gwr =
        reinterpret_cast<const float4*>(w_rec + (size_t)ch * KC * kNRec);
    float4 wa[4], wb[4];
#pragma unroll
    for (int j = 0; j < 4; ++j) {
      wa[j] = gwi[tid + 256 * j];
      wb[j] = gwr[tid + 256 * j];
    }
    if (ch) __syncthreads();  // prior chunk's readers must be done
#pragma unroll
    for (int j = 0; j < 4; ++j) {
      swi4[tid + 256 * j] = wa[j];
      swr4[tid + 256 * j] = wb[j];
    }
    __syncthreads();

#pragma unroll
    for (int kq = 0; kq < KC / 4; ++kq) {
      const int kg = ch * (KC / 4) + kq;          // global k-quad
      const int kn = (kg + 1 < NQ) ? kg + 1 : kg; // next quad (clamped)
      // Issue next quad's x/z loads before consuming the current one: one
      // full kk-loop (~512 cycles of FMA issue) of latency cover.
      float4 axn[4], azn[4];
#pragma unroll
      for (int i = 0; i < 4; ++i) {
        axn[i] = x4[(size_t)i * NQ + kn];
        azn[i] = z4[(size_t)i * NQ + kn];
      }
      // Scheduling fence: the 8 loads above must stay ISSUED here; without
      // it the machine scheduler sinks them to just-before-use (R2: VGPR=64,
      // pipeline collapsed, 1.2K cy exposed latency per kq).
      __builtin_amdgcn_sched_barrier(0);
#pragma unroll
      for (int kk = 0; kk < 4; ++kk) {
        const int k = kq * 4 + kk;
        const float4 wi0 = *reinterpret_cast<const float4*>(&swi[k][c0]);
        const float4 wi1 = *reinterpret_cast<const float4*>(&swi[k][c0 + 64]);
        const float4 wr0 = *reinterpret_cast<const float4*>(&swr[k][c0]);
        const float4 wr1 = *reinterpret_cast<const float4*>(&swr[k][c0 + 64]);
#pragma unroll
        for (int i = 0; i < 4; ++i) {
          const float a = fcomp(axc[i], kk);
          const float b = fcomp(azc[i], kk);
          acc[i][0] = __fmaf_rn(a, wi0.x, acc[i][0]);
          acc[i][1] = __fmaf_rn(a, wi0.y, acc[i][1]);
          acc[i][2] = __fmaf_rn(a, wi0.z, acc[i][2]);
          acc[i][3] = __fmaf_rn(a, wi0.w, acc[i][3]);
          acc[i][4] = __fmaf_rn(a, wi1.x, acc[i][4]);
          acc[i][5] = __fmaf_rn(a, wi1.y, acc[i][5]);
          acc[i][6] = __fmaf_rn(a, wi1.z, acc[i][6]);
          acc[i][7] = __fmaf_rn(a, wi1.w, acc[i][7]);
          acc[i][0] = __fmaf_rn(b, wr0.x, acc[i][0]);
          acc[i][1] = __fmaf_rn(b, wr0.y, acc[i][1]);
          acc[i][2] = __fmaf_rn(b, wr0.z, acc[i][2]);
          acc[i][3] = __fmaf_rn(b, wr0.w, acc[i][3]);
          acc[i][4] = __fmaf_rn(b, wr1.x, acc[i][4]);
          acc[i][5] = __fmaf_rn(b, wr1.y, acc[i][5]);
          acc[i][6] = __fmaf_rn(b, wr1.z, acc[i][6]);
          acc[i][7] = __fmaf_rn(b, wr1.w, acc[i][7]);
        }
      }
#pragma unroll
      for (int i = 0; i < 4; ++i) {  // rotate pipeline (renamed, no movs)
        axc[i] = axn[i];
        azc[i] = azn[i];
      }
    }
  }

  // decay**e table, e in [0,7]: t in [0,4] -> exponent new_t+1 <= 6.
  float ptab[8];
  {
    double d = 1.0;
    const double base = (double)0.95f;
#pragma unroll
    for (int j = 0; j < 8; ++j) {
      ptab[j] = (float)d;
      d *= base;
    }
  }

  const size_t BN = (size_t)batch * kNRec;
  float* __restrict__ out_z = out;
  float* __restrict__ out_v = out + BN;
  float* __restrict__ out_t = out + 2 * BN;

#pragma unroll
  for (int i = 0; i < 4; ++i) {
#pragma unroll
    for (int hlf = 0; hlf < 2; ++hlf) {
      const size_t off = (size_t)(row0 + i) * kNRec + c0 + hlf * 64;
      const vfloat4 vv =
          __builtin_nontemporal_load(reinterpret_cast<const vfloat4*>(v + off));
      const vfloat4 tt =
          __builtin_nontemporal_load(reinterpret_cast<const vfloat4*>(t + off));
      const vfloat4 zz = *reinterpret_cast<const vfloat4*>(z + off);
      float oz[4], ov[4], ot[4];
#pragma unroll
      for (int c = 0; c < 4; ++c) {
        const float s = acc[i][hlf * 4 + c];           // i_in
        const bool h = (s != 0.0f);                    // h = (i_in != 0)
        const float tcur = tt[c];
        const float ntv = h ? tcur : __fadd_rn(tcur, 1.0f);  // new_t pre-reset
        const float vcur = vv[c];
        const float zcur = zz[c];
        // new_v = v * (1 - z)
        float nv = __fmul_rn(vcur, __fsub_rn(1.0f, zcur));
        // clamp below -1: new_v -= (1 - (v > -1)) * (v + 1)
        const float lp = (vcur > -1.0f) ? 1.0f : 0.0f;
        nv = __fsub_rn(nv,
                       __fmul_rn(__fsub_rn(1.0f, lp), __fadd_rn(vcur, 1.0f)));
        // new_v *= decay ** (h * (new_t + 1))
        int ei = h ? (int)__fadd_rn(ntv, 1.0f) : 0;
        ei = ei < 0 ? 0 : (ei > 7 ? 7 : ei);
        nv = __fmul_rn(nv, ptab[ei]);
        // new_v += i_in
        nv = __fadd_rn(nv, s);
        // new_z = spike((new_v - THR)/THR)  <=>  new_v > THR
        oz[c] = (nv > 0.4f) ? 1.0f : 0.0f;
        ov[c] = nv;
        ot[c] = h ? 0.0f : ntv;  // new_t *= (h != 1)
      }
      nt_store4(out_z + off, oz[0], oz[1], oz[2], oz[3]);
      nt_store4(out_v + off, ov[0], ov[1], ov[2], ov[3]);
      nt_store4(out_t + off, ot[0], ot[1], ot[2], ot[3]);
    }
  }
}

}  // namespace

extern "C" void kernel_launch(void* const* d_in, const int* in_sizes, int n_in,
                              void* d_out, int out_size, void* d_ws, size_t ws_size,
                              hipStream_t stream) {
  const float* x = (const float*)d_in[0];
  const float* z = (const float*)d_in[1];
  const float* v = (const float*)d_in[2];
  const float* t = (const float*)d_in[3];
  const float* w_in = (const float*)d_in[4];
  const float* w_rec = (const float*)d_in[5];
  float* out = (float*)d_out;

  const int batch = in_sizes[0] / kNIn;  // 131072
  const int blocks = batch / BR;         // 2048 blocks of 64 rows
  lif_fused<<<blocks, 256, 0, stream>>>(x, z, v, t, w_in, w_rec, out, batch);
}

// Round 4
// 1266.102 us; speedup vs baseline: 1.3713x; 1.3713x over previous
//
#include <hip/hip_runtime.h>

namespace {

constexpr int kNIn = 128;
constexpr int kNRec = 128;
constexpr int BR = 64;              // rows per block
constexpr int KC = 16;              // k-chunk staged in LDS (16 KB total)
constexpr int NCH = kNIn / KC;      // 8 chunks
constexpr int NQ = kNIn / 4;        // 32 k-quads over the whole k range

typedef float vfloat4 __attribute__((ext_vector_type(4)));

__device__ __forceinline__ float fcomp(const float4 f, int i) {
  switch (i & 3) {
    case 0: return f.x;
    case 1: return f.y;
    case 2: return f.z;
    default: return f.w;
  }
}

__device__ __forceinline__ void nt_store4(float* p, float a, float b, float c,
                                          float d) {
  vfloat4 val = {a, b, c, d};
  __builtin_nontemporal_store(val, reinterpret_cast<vfloat4*>(p));
}

// Block: 256 threads, tile 64 rows x 128 cols; thread tile 4 rows x 8 cols
// (cols c0..c0+3 and c0+64..c0+67 so LDS weight reads are 16 contiguous
// lanes x 16B = 2-way bank aliasing = free).
//
// R3 post-mortem: sched_barrier(0) order-pinning made the allocator SPILL
// the pinned prefetch registers to scratch (FETCH 1.9GB / WRITE 3.2GB of
// spill traffic, 5.3x slower). ILP-by-hand is dead on this compiler.
// R4 strategy: hide load latency with TLP instead. KC 32->16 halves LDS
// to 16 KB/block; __launch_bounds__(256,8) lifts the wave cap to 8/SIMD
// -> 8 blocks/CU = 32 waves (was 4 blocks/16 waves, 41% occupancy).
// VGPR cap at 8 waves/EU is 64 = what this structure already compiles to.
// Plain just-in-time loads; no manual pipeline, no fences.
// NT stores (R2: cached stores add 77MB RFO fetch, zero time benefit).
__global__ __launch_bounds__(256, 8) void lif_fused(
    const float* __restrict__ x, const float* __restrict__ z,
    const float* __restrict__ v, const float* __restrict__ t,
    const float* __restrict__ w_in, const float* __restrict__ w_rec,
    float* __restrict__ out, int batch) {
  __shared__ float swi[KC][kNRec];
  __shared__ float swr[KC][kNRec];

  const int tid = threadIdx.x;
  const int tc = tid & 15;          // 16 col groups
  const int tr = tid >> 4;          // 16 row groups x 4 rows = 64 rows
  const int row0 = blockIdx.x * BR + tr * 4;
  const int c0 = tc * 4;

  float acc[4][8];
#pragma unroll
  for (int i = 0; i < 4; ++i)
#pragma unroll
    for (int c = 0; c < 8; ++c) acc[i][c] = 0.0f;

  const float4* __restrict__ x4 =
      reinterpret_cast<const float4*>(x) + (size_t)row0 * NQ;
  const float4* __restrict__ z4 =
      reinterpret_cast<const float4*>(z) + (size_t)row0 * NQ;
  float4* swi4 = reinterpret_cast<float4*>(&swi[0][0]);
  float4* swr4 = reinterpret_cast<float4*>(&swr[0][0]);

  for (int ch = 0; ch < NCH; ++ch) {
    // Stage this chunk's weight rows (KC x 128 per matrix) into LDS.
    // KC=16: 512 float4 per matrix, 2 per thread. Loads issued before the
    // chunk-open barrier so they fly during it.
    const float4* gwi =
        reinterpret_cast<const float4*>(w_in + (size_t)ch * KC * kNRec);
    const float4* gwr =
        reinterpret_cast<const float4*>(w_rec + (size_t)ch * KC * kNRec);
    float4 wa[2], wb[2];
#pragma unroll
    for (int j = 0; j < 2; ++j) {
      wa[j] = gwi[tid + 256 * j];
      wb[j] = gwr[tid + 256 * j];
    }
    if (ch) __syncthreads();  // prior chunk's readers must be done
#pragma unroll
    for (int j = 0; j < 2; ++j) {
      swi4[tid + 256 * j] = wa[j];
      swr4[tid + 256 * j] = wb[j];
    }
    __syncthreads();

#pragma unroll
    for (int kq = 0; kq < KC / 4; ++kq) {
      const int kg = ch * (KC / 4) + kq;  // global k-quad
      float4 ax[4], az[4];
#pragma unroll
      for (int i = 0; i < 4; ++i) {
        ax[i] = x4[(size_t)i * NQ + kg];
        az[i] = z4[(size_t)i * NQ + kg];
      }
#pragma unroll
      for (int kk = 0; kk < 4; ++kk) {
        const int k = kq * 4 + kk;
        const float4 wi0 = *reinterpret_cast<const float4*>(&swi[k][c0]);
        const float4 wi1 = *reinterpret_cast<const float4*>(&swi[k][c0 + 64]);
        const float4 wr0 = *reinterpret_cast<const float4*>(&swr[k][c0]);
        const float4 wr1 = *reinterpret_cast<const float4*>(&swr[k][c0 + 64]);
#pragma unroll
        for (int i = 0; i < 4; ++i) {
          const float a = fcomp(ax[i], kk);
          const float b = fcomp(az[i], kk);
          acc[i][0] = __fmaf_rn(a, wi0.x, acc[i][0]);
          acc[i][1] = __fmaf_rn(a, wi0.y, acc[i][1]);
          acc[i][2] = __fmaf_rn(a, wi0.z, acc[i][2]);
          acc[i][3] = __fmaf_rn(a, wi0.w, acc[i][3]);
          acc[i][4] = __fmaf_rn(a, wi1.x, acc[i][4]);
          acc[i][5] = __fmaf_rn(a, wi1.y, acc[i][5]);
          acc[i][6] = __fmaf_rn(a, wi1.z, acc[i][6]);
          acc[i][7] = __fmaf_rn(a, wi1.w, acc[i][7]);
          acc[i][0] = __fmaf_rn(b, wr0.x, acc[i][0]);
          acc[i][1] = __fmaf_rn(b, wr0.y, acc[i][1]);
          acc[i][2] = __fmaf_rn(b, wr0.z, acc[i][2]);
          acc[i][3] = __fmaf_rn(b, wr0.w, acc[i][3]);
          acc[i][4] = __fmaf_rn(b, wr1.x, acc[i][4]);
          acc[i][5] = __fmaf_rn(b, wr1.y, acc[i][5]);
          acc[i][6] = __fmaf_rn(b, wr1.z, acc[i][6]);
          acc[i][7] = __fmaf_rn(b, wr1.w, acc[i][7]);
        }
      }
    }
  }

  // decay**e table, e in [0,7]: t in [0,4] -> exponent new_t+1 <= 6.
  float ptab[8];
  {
    double d = 1.0;
    const double base = (double)0.95f;
#pragma unroll
    for (int j = 0; j < 8; ++j) {
      ptab[j] = (float)d;
      d *= base;
    }
  }

  const size_t BN = (size_t)batch * kNRec;
  float* __restrict__ out_z = out;
  float* __restrict__ out_v = out + BN;
  float* __restrict__ out_t = out + 2 * BN;

#pragma unroll
  for (int i = 0; i < 4; ++i) {
#pragma unroll
    for (int hlf = 0; hlf < 2; ++hlf) {
      const size_t off = (size_t)(row0 + i) * kNRec + c0 + hlf * 64;
      const vfloat4 vv =
          __builtin_nontemporal_load(reinterpret_cast<const vfloat4*>(v + off));
      const vfloat4 tt =
          __builtin_nontemporal_load(reinterpret_cast<const vfloat4*>(t + off));
      const vfloat4 zz = *reinterpret_cast<const vfloat4*>(z + off);
      float oz[4], ov[4], ot[4];
#pragma unroll
      for (int c = 0; c < 4; ++c) {
        const float s = acc[i][hlf * 4 + c];           // i_in
        const bool h = (s != 0.0f);                    // h = (i_in != 0)
        const float tcur = tt[c];
        const float ntv = h ? tcur : __fadd_rn(tcur, 1.0f);  // new_t pre-reset
        const float vcur = vv[c];
        const float zcur = zz[c];
        // new_v = v * (1 - z)
        float nv = __fmul_rn(vcur, __fsub_rn(1.0f, zcur));
        // clamp below -1: new_v -= (1 - (v > -1)) * (v + 1)
        const float lp = (vcur > -1.0f) ? 1.0f : 0.0f;
        nv = __fsub_rn(nv,
                       __fmul_rn(__fsub_rn(1.0f, lp), __fadd_rn(vcur, 1.0f)));
        // new_v *= decay ** (h * (new_t + 1))
        int ei = h ? (int)__fadd_rn(ntv, 1.0f) : 0;
        ei = ei < 0 ? 0 : (ei > 7 ? 7 : ei);
        nv = __fmul_rn(nv, ptab[ei]);
        // new_v += i_in
        nv = __fadd_rn(nv, s);
        // new_z = spike((new_v - THR)/THR)  <=>  new_v > THR
        oz[c] = (nv > 0.4f) ? 1.0f : 0.0f;
        ov[c] = nv;
        ot[c] = h ? 0.0f : ntv;  // new_t *= (h != 1)
      }
      nt_store4(out_z + off, oz[0], oz[1], oz[2], oz[3]);
      nt_store4(out_v + off, ov[0], ov[1], ov[2], ov[3]);
      nt_store4(out_t + off, ot[0], ot[1], ot[2], ot[3]);
    }
  }
}

}  // namespace

extern "C" void kernel_launch(void* const* d_in, const int* in_sizes, int n_in,
                              void* d_out, int out_size, void* d_ws, size_t ws_size,
                              hipStream_t stream) {
  const float* x = (const float*)d_in[0];
  const float* z = (const float*)d_in[1];
  const float* v = (const float*)d_in[2];
  const float* t = (const float*)d_in[3];
  const float* w_in = (const float*)d_in[4];
  const float* w_rec = (const float*)d_in[5];
  float* out = (float*)d_out;

  const int batch = in_sizes[0] / kNIn;  // 131072
  const int blocks = batch / BR;         // 2048 blocks of 64 rows
  lif_fused<<<blocks, 256, 0, stream>>>(x, z, v, t, w_in, w_rec, out, batch);
}

// Round 5
// 616.398 us; speedup vs baseline: 2.8167x; 2.0540x over previous
//
#include <hip/hip_runtime.h>

namespace {

constexpr int kNIn = 128;
constexpr int kNRec = 128;
constexpr int BR = 64;              // rows per block
constexpr int KC = 16;              // k-chunk staged in LDS (16 KB total)
constexpr int NCH = kNIn / KC;      // 8 chunks
constexpr int NQ = kNIn / 4;        // 32 k-quads over the whole k range

typedef float vfloat4 __attribute__((ext_vector_type(4)));

__device__ __forceinline__ float fcomp(const float4 f, int i) {
  switch (i & 3) {
    case 0: return f.x;
    case 1: return f.y;
    case 2: return f.z;
    default: return f.w;
  }
}

__device__ __forceinline__ void nt_store4(float* p, float a, float b, float c,
                                          float d) {
  vfloat4 val = {a, b, c, d};
  __builtin_nontemporal_store(val, reinterpret_cast<vfloat4*>(p));
}

// Block: 256 threads, tile 64 rows x 128 cols; thread tile 4 rows x 8 cols
// (cols c0..c0+3 and c0+64..c0+67 so LDS weight reads are 16 contiguous
// lanes x 16B = 2-way bank aliasing = free).
//
// Occupancy/VGPR trade-off measured across rounds:
//   launch_bounds(256,4): cap 128 -> VGPR 56-64, no spill, 16 waves/CU
//                         (41% occ), 284us  [latency-bound]
//   launch_bounds(256,8): cap  64 -> allocator SPILLS acc to scratch
//                         (VGPR 32, 4.1GB spill traffic), 1014us
// This version: launch_bounds(256,6) -> cap 85. Natural ~60-64 fits with
// margin (no spill), wave ceiling 24/CU (75%). KC=16 keeps LDS at
// 16KB/block so 6 blocks/CU fit (96KB < 160KB).
// Plain just-in-time loads (R3: sched_barrier pinning forces spills).
// NT stores (R2: cached stores add 77MB RFO fetch, zero time benefit).
__global__ __launch_bounds__(256, 6) void lif_fused(
    const float* __restrict__ x, const float* __restrict__ z,
    const float* __restrict__ v, const float* __restrict__ t,
    const float* __restrict__ w_in, const float* __restrict__ w_rec,
    float* __restrict__ out, int batch) {
  __shared__ float swi[KC][kNRec];
  __shared__ float swr[KC][kNRec];

  const int tid = threadIdx.x;
  const int tc = tid & 15;          // 16 col groups
  const int tr = tid >> 4;          // 16 row groups x 4 rows = 64 rows
  const int row0 = blockIdx.x * BR + tr * 4;
  const int c0 = tc * 4;

  float acc[4][8];
#pragma unroll
  for (int i = 0; i < 4; ++i)
#pragma unroll
    for (int c = 0; c < 8; ++c) acc[i][c] = 0.0f;

  const float4* __restrict__ x4 =
      reinterpret_cast<const float4*>(x) + (size_t)row0 * NQ;
  const float4* __restrict__ z4 =
      reinterpret_cast<const float4*>(z) + (size_t)row0 * NQ;
  float4* swi4 = reinterpret_cast<float4*>(&swi[0][0]);
  float4* swr4 = reinterpret_cast<float4*>(&swr[0][0]);

  for (int ch = 0; ch < NCH; ++ch) {
    // Stage this chunk's weight rows (KC x 128 per matrix) into LDS.
    // KC=16: 512 float4 per matrix, 2 per thread. Loads issued before the
    // chunk-open barrier so they fly during it.
    const float4* gwi =
        reinterpret_cast<const float4*>(w_in + (size_t)ch * KC * kNRec);
    const float4* gwr =
        reinterpret_cast<const float4*>(w_rec + (size_t)ch * KC * kNRec);
    float4 wa[2], wb[2];
#pragma unroll
    for (int j = 0; j < 2; ++j) {
      wa[j] = gwi[tid + 256 * j];
      wb[j] = gwr[tid + 256 * j];
    }
    if (ch) __syncthreads();  // prior chunk's readers must be done
#pragma unroll
    for (int j = 0; j < 2; ++j) {
      swi4[tid + 256 * j] = wa[j];
      swr4[tid + 256 * j] = wb[j];
    }
    __syncthreads();

#pragma unroll
    for (int kq = 0; kq < KC / 4; ++kq) {
      const int kg = ch * (KC / 4) + kq;  // global k-quad
      float4 ax[4], az[4];
#pragma unroll
      for (int i = 0; i < 4; ++i) {
        ax[i] = x4[(size_t)i * NQ + kg];
        az[i] = z4[(size_t)i * NQ + kg];
      }
#pragma unroll
      for (int kk = 0; kk < 4; ++kk) {
        const int k = kq * 4 + kk;
        const float4 wi0 = *reinterpret_cast<const float4*>(&swi[k][c0]);
        const float4 wi1 = *reinterpret_cast<const float4*>(&swi[k][c0 + 64]);
        const float4 wr0 = *reinterpret_cast<const float4*>(&swr[k][c0]);
        const float4 wr1 = *reinterpret_cast<const float4*>(&swr[k][c0 + 64]);
#pragma unroll
        for (int i = 0; i < 4; ++i) {
          const float a = fcomp(ax[i], kk);
          const float b = fcomp(az[i], kk);
          acc[i][0] = __fmaf_rn(a, wi0.x, acc[i][0]);
          acc[i][1] = __fmaf_rn(a, wi0.y, acc[i][1]);
          acc[i][2] = __fmaf_rn(a, wi0.z, acc[i][2]);
          acc[i][3] = __fmaf_rn(a, wi0.w, acc[i][3]);
          acc[i][4] = __fmaf_rn(a, wi1.x, acc[i][4]);
          acc[i][5] = __fmaf_rn(a, wi1.y, acc[i][5]);
          acc[i][6] = __fmaf_rn(a, wi1.z, acc[i][6]);
          acc[i][7] = __fmaf_rn(a, wi1.w, acc[i][7]);
          acc[i][0] = __fmaf_rn(b, wr0.x, acc[i][0]);
          acc[i][1] = __fmaf_rn(b, wr0.y, acc[i][1]);
          acc[i][2] = __fmaf_rn(b, wr0.z, acc[i][2]);
          acc[i][3] = __fmaf_rn(b, wr0.w, acc[i][3]);
          acc[i][4] = __fmaf_rn(b, wr1.x, acc[i][4]);
          acc[i][5] = __fmaf_rn(b, wr1.y, acc[i][5]);
          acc[i][6] = __fmaf_rn(b, wr1.z, acc[i][6]);
          acc[i][7] = __fmaf_rn(b, wr1.w, acc[i][7]);
        }
      }
    }
  }

  // decay**e table, e in [0,7]: t in [0,4] -> exponent new_t+1 <= 6.
  float ptab[8];
  {
    double d = 1.0;
    const double base = (double)0.95f;
#pragma unroll
    for (int j = 0; j < 8; ++j) {
      ptab[j] = (float)d;
      d *= base;
    }
  }

  const size_t BN = (size_t)batch * kNRec;
  float* __restrict__ out_z = out;
  float* __restrict__ out_v = out + BN;
  float* __restrict__ out_t = out + 2 * BN;

#pragma unroll
  for (int i = 0; i < 4; ++i) {
#pragma unroll
    for (int hlf = 0; hlf < 2; ++hlf) {
      const size_t off = (size_t)(row0 + i) * kNRec + c0 + hlf * 64;
      const vfloat4 vv =
          __builtin_nontemporal_load(reinterpret_cast<const vfloat4*>(v + off));
      const vfloat4 tt =
          __builtin_nontemporal_load(reinterpret_cast<const vfloat4*>(t + off));
      const vfloat4 zz = *reinterpret_cast<const vfloat4*>(z + off);
      float oz[4], ov[4], ot[4];
#pragma unroll
      for (int c = 0; c < 4; ++c) {
        const float s = acc[i][hlf * 4 + c];           // i_in
        const bool h = (s != 0.0f);                    // h = (i_in != 0)
        const float tcur = tt[c];
        const float ntv = h ? tcur : __fadd_rn(tcur, 1.0f);  // new_t pre-reset
        const float vcur = vv[c];
        const float zcur = zz[c];
        // new_v = v * (1 - z)
        float nv = __fmul_rn(vcur, __fsub_rn(1.0f, zcur));
        // clamp below -1: new_v -= (1 - (v > -1)) * (v + 1)
        const float lp = (vcur > -1.0f) ? 1.0f : 0.0f;
        nv = __fsub_rn(nv,
                       __fmul_rn(__fsub_rn(1.0f, lp), __fadd_rn(vcur, 1.0f)));
        // new_v *= decay ** (h * (new_t + 1))
        int ei = h ? (int)__fadd_rn(ntv, 1.0f) : 0;
        ei = ei < 0 ? 0 : (ei > 7 ? 7 : ei);
        nv = __fmul_rn(nv, ptab[ei]);
        // new_v += i_in
        nv = __fadd_rn(nv, s);
        // new_z = spike((new_v - THR)/THR)  <=>  new_v > THR
        oz[c] = (nv > 0.4f) ? 1.0f : 0.0f;
        ov[c] = nv;
        ot[c] = h ? 0.0f : ntv;  // new_t *= (h != 1)
      }
      nt_store4(out_z + off, oz[0], oz[1], oz[2], oz[3]);
      nt_store4(out_v + off, ov[0], ov[1], ov[2], ov[3]);
      nt_store4(out_t + off, ot[0], ot[1], ot[2], ot[3]);
    }
  }
}

}  // namespace

extern "C" void kernel_launch(void* const* d_in, const int* in_sizes, int n_in,
                              void* d_out, int out_size, void* d_ws, size_t ws_size,
                              hipStream_t stream) {
  const float* x = (const float*)d_in[0];
  const float* z = (const float*)d_in[1];
  const float* v = (const float*)d_in[2];
  const float* t = (const float*)d_in[3];
  const float* w_in = (const float*)d_in[4];
  const float* w_rec = (const float*)d_in[5];
  float* out = (float*)d_out;

  const int batch = in_sizes[0] / kNIn;  // 131072
  const int blocks = batch / BR;         // 2048 blocks of 64 rows
  lif_fused<<<blocks, 256, 0, stream>>>(x, z, v, t, w_in, w_rec, out, batch);
}

// Round 6
// 450.571 us; speedup vs baseline: 3.8534x; 1.3680x over previous
//
#include <hip/hip_runtime.h>

namespace {

constexpr int kNIn = 128;
constexpr int kNRec = 128;
constexpr int BR = 64;              // rows per block
constexpr int KC = 16;              // k-chunk staged in LDS
constexpr int NCH = kNIn / KC;      // 8 chunks

typedef float vfloat4 __attribute__((ext_vector_type(4)));

__device__ __forceinline__ float fcomp(const float4 f, int i) {
  switch (i & 3) {
    case 0: return f.x;
    case 1: return f.y;
    case 2: return f.z;
    default: return f.w;
  }
}

__device__ __forceinline__ void nt_store4(float* p, float a, float b, float c,
                                          float d) {
  vfloat4 val = {a, b, c, d};
  __builtin_nontemporal_store(val, reinterpret_cast<vfloat4*>(p));
}

// Block: 256 threads, tile 64 rows x 128 cols; thread tile 4 rows x 8 cols.
//
// Round-6 structure: ALL inner-loop operands come from LDS. x/z chunk
// tiles are staged TRANSPOSED (sxT[k][row]) so one ds_read_b128 at
// sxT[k][4*tr] yields the thread's 4 rows for that k; across a wave the
// 4 tr-groups hit banks {0-3,4-7,8-11,12-15} + 16-lane broadcast =
// conflict-free with no padding. Staging is pinned by the chunk barriers
// (scheduler cannot sink it), so no persistent prefetch registers are
// needed -- the R2/R3/R5 failure lane (allocator spills / squeezes any
// register-based pipeline) is bypassed entirely. Global x/z load
// instruction count also drops 16x (each element read once per block).
// LDS = 2x8KB weights + 2x4KB x/z = 24KB -> 6 blocks/CU = 24 waves (75%)
// at the never-spilled launch_bounds(256,4).
// History: (256,6)/(256,8) spill (R5/R4); sched_barrier pinning spills
// (R3); cached stores add RFO fetch at zero benefit (R2); NT stores kept.
// FMA order ch->kq->kk->i->cols is IDENTICAL to the verified baseline ->
// bit-identical output (absmax 0.0078125).
__global__ __launch_bounds__(256, 4) void lif_fused(
    const float* __restrict__ x, const float* __restrict__ z,
    const float* __restrict__ v, const float* __restrict__ t,
    const float* __restrict__ w_in, const float* __restrict__ w_rec,
    float* __restrict__ out, int batch) {
  __shared__ float swi[KC][kNRec];   // 8 KB
  __shared__ float swr[KC][kNRec];   // 8 KB
  __shared__ float sxT[KC][BR];      // 4 KB, transposed: [k][row]
  __shared__ float szT[KC][BR];      // 4 KB

  const int tid = threadIdx.x;
  const int tc = tid & 15;          // 16 col groups
  const int tr = tid >> 4;          // 16 row groups x 4 rows = 64 rows
  const int brow = blockIdx.x * BR;
  const int row0 = brow + tr * 4;
  const int c0 = tc * 4;

  // staging coordinates: thread tid covers row srow, k-quad sq of chunk
  const int srow = tid >> 2;        // 0..63
  const int sq = tid & 3;           // 0..3 (quad of k within chunk)

  float acc[4][8];
#pragma unroll
  for (int i = 0; i < 4; ++i)
#pragma unroll
    for (int c = 0; c < 8; ++c) acc[i][c] = 0.0f;

  float4* swi4 = reinterpret_cast<float4*>(&swi[0][0]);
  float4* swr4 = reinterpret_cast<float4*>(&swr[0][0]);

  for (int ch = 0; ch < NCH; ++ch) {
    // ---- stage weights (KC x 128 each) + x/z tiles (64 x KC each) ----
    // Global loads issued before the chunk-open barrier so they overlap
    // the previous chunk's FMA tail (barrier-pinned async-stage split).
    const float4* gwi =
        reinterpret_cast<const float4*>(w_in + (size_t)ch * KC * kNRec);
    const float4* gwr =
        reinterpret_cast<const float4*>(w_rec + (size_t)ch * KC * kNRec);
    float4 wa[2], wb[2];
#pragma unroll
    for (int j = 0; j < 2; ++j) {
      wa[j] = gwi[tid + 256 * j];
      wb[j] = gwr[tid + 256 * j];
    }
    const float4 xv = *reinterpret_cast<const float4*>(
        x + (size_t)(brow + srow) * kNIn + ch * KC + sq * 4);
    const float4 zv = *reinterpret_cast<const float4*>(
        z + (size_t)(brow + srow) * kNRec + ch * KC + sq * 4);

    if (ch) __syncthreads();  // prior chunk's readers must be done
#pragma unroll
    for (int j = 0; j < 2; ++j) {
      swi4[tid + 256 * j] = wa[j];
      swr4[tid + 256 * j] = wb[j];
    }
#pragma unroll
    for (int j = 0; j < 4; ++j) {   // transpose into [k][row]
      sxT[sq * 4 + j][srow] = fcomp(xv, j);
      szT[sq * 4 + j][srow] = fcomp(zv, j);
    }
    __syncthreads();

    // ---- compute: pure LDS operands ----
#pragma unroll
    for (int kq = 0; kq < KC / 4; ++kq) {
#pragma unroll
      for (int kk = 0; kk < 4; ++kk) {
        const int k = kq * 4 + kk;
        const float4 xk = *reinterpret_cast<const float4*>(&sxT[k][tr * 4]);
        const float4 zk = *reinterpret_cast<const float4*>(&szT[k][tr * 4]);
        const float4 wi0 = *reinterpret_cast<const float4*>(&swi[k][c0]);
        const float4 wi1 = *reinterpret_cast<const float4*>(&swi[k][c0 + 64]);
        const float4 wr0 = *reinterpret_cast<const float4*>(&swr[k][c0]);
        const float4 wr1 = *reinterpret_cast<const float4*>(&swr[k][c0 + 64]);
#pragma unroll
        for (int i = 0; i < 4; ++i) {
          const float a = fcomp(xk, i);
          const float b = fcomp(zk, i);
          acc[i][0] = __fmaf_rn(a, wi0.x, acc[i][0]);
          acc[i][1] = __fmaf_rn(a, wi0.y, acc[i][1]);
          acc[i][2] = __fmaf_rn(a, wi0.z, acc[i][2]);
          acc[i][3] = __fmaf_rn(a, wi0.w, acc[i][3]);
          acc[i][4] = __fmaf_rn(a, wi1.x, acc[i][4]);
          acc[i][5] = __fmaf_rn(a, wi1.y, acc[i][5]);
          acc[i][6] = __fmaf_rn(a, wi1.z, acc[i][6]);
          acc[i][7] = __fmaf_rn(a, wi1.w, acc[i][7]);
          acc[i][0] = __fmaf_rn(b, wr0.x, acc[i][0]);
          acc[i][1] = __fmaf_rn(b, wr0.y, acc[i][1]);
          acc[i][2] = __fmaf_rn(b, wr0.z, acc[i][2]);
          acc[i][3] = __fmaf_rn(b, wr0.w, acc[i][3]);
          acc[i][4] = __fmaf_rn(b, wr1.x, acc[i][4]);
          acc[i][5] = __fmaf_rn(b, wr1.y, acc[i][5]);
          acc[i][6] = __fmaf_rn(b, wr1.z, acc[i][6]);
          acc[i][7] = __fmaf_rn(b, wr1.w, acc[i][7]);
        }
      }
    }
  }

  // decay**e table, e in [0,7]: t in [0,4] -> exponent new_t+1 <= 6.
  float ptab[8];
  {
    double d = 1.0;
    const double base = (double)0.95f;
#pragma unroll
    for (int j = 0; j < 8; ++j) {
      ptab[j] = (float)d;
      d *= base;
    }
  }

  const size_t BN = (size_t)batch * kNRec;
  float* __restrict__ out_z = out;
  float* __restrict__ out_v = out + BN;
  float* __restrict__ out_t = out + 2 * BN;

#pragma unroll
  for (int i = 0; i < 4; ++i) {
#pragma unroll
    for (int hlf = 0; hlf < 2; ++hlf) {
      const size_t off = (size_t)(row0 + i) * kNRec + c0 + hlf * 64;
      const vfloat4 vv =
          __builtin_nontemporal_load(reinterpret_cast<const vfloat4*>(v + off));
      const vfloat4 tt =
          __builtin_nontemporal_load(reinterpret_cast<const vfloat4*>(t + off));
      const vfloat4 zz = *reinterpret_cast<const vfloat4*>(z + off);
      float oz[4], ov[4], ot[4];
#pragma unroll
      for (int c = 0; c < 4; ++c) {
        const float s = acc[i][hlf * 4 + c];           // i_in
        const bool h = (s != 0.0f);                    // h = (i_in != 0)
        const float tcur = tt[c];
        const float ntv = h ? tcur : __fadd_rn(tcur, 1.0f);  // new_t pre-reset
        const float vcur = vv[c];
        const float zcur = zz[c];
        // new_v = v * (1 - z)
        float nv = __fmul_rn(vcur, __fsub_rn(1.0f, zcur));
        // clamp below -1: new_v -= (1 - (v > -1)) * (v + 1)
        const float lp = (vcur > -1.0f) ? 1.0f : 0.0f;
        nv = __fsub_rn(nv,
                       __fmul_rn(__fsub_rn(1.0f, lp), __fadd_rn(vcur, 1.0f)));
        // new_v *= decay ** (h * (new_t + 1))
        int ei = h ? (int)__fadd_rn(ntv, 1.0f) : 0;
        ei = ei < 0 ? 0 : (ei > 7 ? 7 : ei);
        nv = __fmul_rn(nv, ptab[ei]);
        // new_v += i_in
        nv = __fadd_rn(nv, s);
        // new_z = spike((new_v - THR)/THR)  <=>  new_v > THR
        oz[c] = (nv > 0.4f) ? 1.0f : 0.0f;
        ov[c] = nv;
        ot[c] = h ? 0.0f : ntv;  // new_t *= (h != 1)
      }
      nt_store4(out_z + off, oz[0], oz[1], oz[2], oz[3]);
      nt_store4(out_v + off, ov[0], ov[1], ov[2], ov[3]);
      nt_store4(out_t + off, ot[0], ot[1], ot[2], ot[3]);
    }
  }
}

}  // namespace

extern "C" void kernel_launch(void* const* d_in, const int* in_sizes, int n_in,
                              void* d_out, int out_size, void* d_ws, size_t ws_size,
                              hipStream_t stream) {
  const float* x = (const float*)d_in[0];
  const float* z = (const float*)d_in[1];
  const float* v = (const float*)d_in[2];
  const float* t = (const float*)d_in[3];
  const float* w_in = (const float*)d_in[4];
  const float* w_rec = (const float*)d_in[5];
  float* out = (float*)d_out;

  const int batch = in_sizes[0] / kNIn;  // 131072
  const int blocks = batch / BR;         // 2048 blocks of 64 rows
  lif_fused<<<blocks, 256, 0, stream>>>(x, z, v, t, w_in, w_rec, out, batch);
}